// Round 16
// baseline (94.261 us; speedup 1.0000x reference)
//
#include <hip/hip_runtime.h>

#define N_NODES 50000
#define IN_DIM 64
#define OUT_DIM 128
#define N_EDGES 800000

#define NPART 1024                  // histogram partitions
#define EPP 782                     // ceil(N_EDGES / NPART)
#define NPLACE 256                  // place blocks (4 hist partitions each)
#define NBUCK 391                   // ceil(50000/128) buckets of 128 dsts
#define WLDS 136                    // padded bf16 row stride: bank step 4 -> 2-way (free)
#define FIXSCALE 1048576.0f         // 2^20 fixed-point
#define INVFIX (1.0f / 1048576.0f)

typedef __attribute__((ext_vector_type(8))) short bf16x8;
typedef __attribute__((ext_vector_type(4))) float f32x4;

__device__ __forceinline__ unsigned short f2bf(float f) {
    unsigned u = __float_as_uint(f);
    unsigned r = u + 0x7FFFu + ((u >> 16) & 1u);   // round-to-nearest-even
    return (unsigned short)(r >> 16);
}

// acc swizzle: feature f of node nd at acc[nd*64 + (f ^ ((nd&7)<<3))]
__device__ __forceinline__ int SW(int nd, int f) { return (nd << 6) + (f ^ ((nd & 7) << 3)); }

// ---------------- P1: per-(partition,bucket) histogram + tot + x->bf16 + W2->bf16 ----------------
__global__ __launch_bounds__(256) void p1_count_cvt(const int* __restrict__ ei,
                                                    const float* __restrict__ x,
                                                    const float* __restrict__ Wl,
                                                    const float* __restrict__ Wr,
                                                    int* __restrict__ cnt_mat,
                                                    int* __restrict__ tot,
                                                    unsigned short* __restrict__ xh,
                                                    unsigned short* __restrict__ w2h)
{
    __shared__ int h[NBUCK];
    int t = threadIdx.x, blk = blockIdx.x;
    for (int i = t; i < NBUCK; i += 256) h[i] = 0;
    __syncthreads();
    int s = blk * EPP;
    int e_end = min(s + EPP, N_EDGES);
    for (int i = s + t; i < e_end; i += 256)
        atomicAdd(&h[ei[N_EDGES + i] >> 7], 1);
    // x -> bf16, grid-stride over 800000 float4 (~3 iters/thread)
    for (int gi = blk * 256 + t; gi < N_NODES * 16; gi += NPART * 256) {
        float4 v = ((const float4*)x)[gi];
        ushort4 o;
        o.x = f2bf(v.x); o.y = f2bf(v.y); o.z = f2bf(v.z); o.w = f2bf(v.w);
        ((ushort4*)xh)[gi] = o;
    }
    // W2h[o] = [Wr[o] | Wl[o]] bf16 (blocks 0..127, one out-row each)
    if (blk < 128 && t < 64) {
        w2h[blk * 128 + t]      = f2bf(Wr[blk * 64 + t]);
        w2h[blk * 128 + 64 + t] = f2bf(Wl[blk * 64 + t]);
    }
    __syncthreads();
    for (int b = t; b < NBUCK; b += 256) {
        int v = h[b];
        cnt_mat[b * NPART + blk] = v;
        if (v) atomicAdd(&tot[b], v);    // fused rowsum (replaces a 391-block launch)
    }
}

// ---------------- rowscan2: cursors = bucket_start + exclusive scan of row ----------------
__global__ __launch_bounds__(256) void rowscan2(int* __restrict__ cnt_mat,
                                                const int* __restrict__ tot)
{
    __shared__ int bst_s;
    __shared__ int wtot[4];
    int t = threadIdx.x, b = blockIdx.x;
    int lane = t & 63, w = t >> 6;

    int4 mine = ((const int4*)(cnt_mat + b * NPART))[t];
    int s = mine.x + mine.y + mine.z + mine.w;
    int incl = s;
#pragma unroll
    for (int d = 1; d < 64; d <<= 1) {
        int u = __shfl_up(incl, d, 64);
        if (lane >= d) incl += u;
    }
    if (lane == 63) wtot[w] = incl;

    if (w == 0) {                       // redundant exclusive scan of 391 totals
        int carry = 0;
        for (int base = 0; base < NBUCK; base += 64) {   // 7 chunks
            int i = base + lane;
            int v = (i < NBUCK) ? tot[i] : 0;
            int ic = v;
#pragma unroll
            for (int d = 1; d < 64; d <<= 1) {
                int u = __shfl_up(ic, d, 64);
                if (lane >= d) ic += u;
            }
            if (i == b) bst_s = carry + ic - v;
            carry += __shfl(ic, 63, 64);
        }
    }
    __syncthreads();
    int woff = 0;
    for (int j = 0; j < w; ++j) woff += wtot[j];
    int base = bst_s + woff + incl - s;
    int4 outv;
    outv.x = base;
    outv.y = base + mine.x;
    outv.z = base + mine.x + mine.y;
    outv.w = base + mine.x + mine.y + mine.z;
    ((int4*)(cnt_mat + b * NPART))[t] = outv;
}

// ---------------- place: 256 blocks, each covers 4 hist partitions ----------------
__global__ __launch_bounds__(256) void bucket_place(const int* __restrict__ ei,
                                                    const int* __restrict__ cnt_scan,
                                                    unsigned* __restrict__ ebuf)
{
    __shared__ int cur[NBUCK];
    int t = threadIdx.x, blk = blockIdx.x;
    for (int b = t; b < NBUCK; b += 256) cur[b] = cnt_scan[b * NPART + blk * 4];
    __syncthreads();
    int s = blk * 4 * EPP;
    int e_end = min(s + 4 * EPP, N_EDGES);
    for (int i = s + t; i < e_end; i += 256) {
        int src = ei[i], dst = ei[N_EDGES + i];
        int slot = atomicAdd(&cur[dst >> 7], 1);
        ebuf[slot] = (unsigned)src | ((unsigned)(dst & 127) << 16);
    }
}

// ---------------- fused gather (LDS int fixed-point, 16-deep MLP) + MFMA ----------------
__global__ __launch_bounds__(1024) void gather_mfma(const unsigned short* __restrict__ xh,
                                                    const int* __restrict__ cnt_scan,
                                                    const unsigned* __restrict__ ebuf,
                                                    const unsigned short* __restrict__ w2h,
                                                    const float* __restrict__ bl,
                                                    float* __restrict__ out)
{
    __shared__ int acc[128 * 64];                 // 32 KB
    __shared__ unsigned short wlds[128 * WLDS];   // 34.8 KB -> 68.6 KB total, 2 blocks/CU
    __shared__ int dcnt[128];
    __shared__ int range_s[2];
    int t = threadIdx.x, b = blockIdx.x;
    int lane = t & 63, w = t >> 6;                // 16 waves

#pragma unroll
    for (int c = 0; c < 2; ++c) {
        int idx = c * 1024 + t;
        int o = idx >> 4, kc = idx & 15;
        bf16x8 v = *(const bf16x8*)(w2h + o * 128 + kc * 8);
        *(bf16x8*)(&wlds[o * WLDS + kc * 8]) = v;
    }
    if (t == 0) {
        range_s[0] = cnt_scan[b * NPART];
        range_s[1] = (b < NBUCK - 1) ? cnt_scan[(b + 1) * NPART] : N_EDGES;
    }
#pragma unroll
    for (int i = 0; i < 8; ++i) acc[i * 1024 + t] = 0;
    if (t < 128) dcnt[t] = 0;
    __syncthreads();

    int bs = range_s[0], be = range_s[1];

    for (int e = bs + t; e < be; e += 1024)
        atomicAdd(&dcnt[(ebuf[e] >> 16) & 127], 1);

    // 16 outstanding 128B row loads per wave
    for (int e0 = bs + w * 64; e0 < be; e0 += 1024) {
        int m = be - e0; if (m > 64) m = 64;
        unsigned pv = (lane < m) ? ebuf[e0 + lane] : 0u;
        for (int k = 0; k < m; k += 16) {
            unsigned p[16]; int fx[16];
#pragma unroll
            for (int u = 0; u < 16; ++u) p[u] = __shfl(pv, k + u, 64);
#pragma unroll
            for (int u = 0; u < 16; ++u) {
                unsigned short hv = xh[(size_t)(p[u] & 0xFFFFu) * IN_DIM + lane];
                fx[u] = __float2int_rn(__uint_as_float((unsigned)hv << 16) * FIXSCALE);
            }
#pragma unroll
            for (int u = 0; u < 16; ++u)
                if (k + u < m)
                    atomicAdd(&acc[SW((p[u] >> 16) & 127, lane)], fx[u]);
        }
    }
    __syncthreads();

    // -------- MFMA: out = [x | mean] @ W2^T + b --------
    int s_strip = w & 7, hf = w >> 3;
    int nbase = b * 128 + s_strip * 16;
    if (nbase >= N_NODES) return;
    int row = lane & 15, q = lane >> 4;
    int nn = nbase + row;
    size_t nrow = (size_t)((nn < N_NODES) ? nn : (N_NODES - 1));

    bf16x8 a[4];
    a[0] = *(const bf16x8*)(xh + nrow * IN_DIM + q * 8);
    a[1] = *(const bf16x8*)(xh + nrow * IN_DIM + q * 8 + 32);

    int in_node = s_strip * 16 + row;
    int deg = dcnt[in_node];
    float sc = deg ? INVFIX / (float)deg : 0.0f;
    bf16x8 a2, a3;
#pragma unroll
    for (int j = 0; j < 8; ++j) {
        a2[j] = (short)f2bf((float)acc[SW(in_node, q * 8 + j)] * sc);
        a3[j] = (short)f2bf((float)acc[SW(in_node, 32 + q * 8 + j)] * sc);
    }
    a[2] = a2; a[3] = a3;

    f32x4 accf[4];
#pragma unroll
    for (int jj = 0; jj < 4; ++jj) accf[jj] = (f32x4){0.f, 0.f, 0.f, 0.f};

#pragma unroll
    for (int jj = 0; jj < 4; ++jj) {
        int ot = hf * 4 + jj;
        const unsigned short* wb = &wlds[(ot * 16 + row) * WLDS + q * 8];
#pragma unroll
        for (int s = 0; s < 4; ++s) {
            bf16x8 bfrag = *(const bf16x8*)(wb + s * 32);
            accf[jj] = __builtin_amdgcn_mfma_f32_16x16x32_bf16(a[s], bfrag, accf[jj], 0, 0, 0);
        }
    }

#pragma unroll
    for (int jj = 0; jj < 4; ++jj) {
        int ot = hf * 4 + jj;
        float bias = bl[ot * 16 + row];
#pragma unroll
        for (int r = 0; r < 4; ++r) {
            int n = nbase + q * 4 + r;
            if (n < N_NODES)
                out[(size_t)n * OUT_DIM + ot * 16 + row] = accf[jj][r] + bias;
        }
    }
}

extern "C" void kernel_launch(void* const* d_in, const int* in_sizes, int n_in,
                              void* d_out, int out_size, void* d_ws, size_t ws_size,
                              hipStream_t stream) {
    const float* x  = (const float*)d_in[0];
    const int*   ei = (const int*)d_in[1];
    const float* Wl = (const float*)d_in[2];
    const float* bl = (const float*)d_in[3];
    const float* Wr = (const float*)d_in[4];
    float* out = (float*)d_out;

    // ws layout (~11.3 MB):
    int*            cnt_mat = (int*)d_ws;                               // 391*1024 ints
    int*            tot     = cnt_mat + NBUCK * NPART;                  // 392 ints
    unsigned*       ebuf    = (unsigned*)(tot + NBUCK + 1);             // 800000 uints
    unsigned short* xh      = (unsigned short*)(ebuf + N_EDGES);        // 3.2M bf16
    unsigned short* w2h     = xh + (size_t)N_NODES * IN_DIM;            // 16384 bf16

    hipMemsetAsync(tot, 0, (NBUCK + 1) * sizeof(int), stream);
    p1_count_cvt<<<NPART, 256, 0, stream>>>(ei, x, Wl, Wr, cnt_mat, tot, xh, w2h);
    rowscan2<<<NBUCK, 256, 0, stream>>>(cnt_mat, tot);
    bucket_place<<<NPLACE, 256, 0, stream>>>(ei, cnt_mat, ebuf);
    gather_mfma<<<NBUCK, 1024, 0, stream>>>(xh, cnt_mat, ebuf, w2h, bl, out);
}

// Round 17
// 68.774 us; speedup vs baseline: 1.3706x; 1.3706x over previous
//
#include <hip/hip_runtime.h>

#define N_NODES 50000
#define IN_DIM 64
#define OUT_DIM 128
#define N_EDGES 800000

#define NPART 1024                  // histogram partitions
#define EPP 782                     // ceil(N_EDGES / NPART)
#define NPLACE 256                  // place blocks (4 hist partitions each)
#define NBUCK 512                   // buckets: exactly 2 blocks/CU on 256 CUs
#define NPB 98                      // nodes per bucket (512*98 = 50176 >= 50000)
#define WLDS 136                    // padded bf16 row stride: bank step 4 -> 2-way (free)
#define FIXSCALE 1048576.0f         // 2^20 fixed-point
#define INVFIX (1.0f / 1048576.0f)

typedef __attribute__((ext_vector_type(8))) short bf16x8;
typedef __attribute__((ext_vector_type(4))) float f32x4;

__device__ __forceinline__ unsigned short f2bf(float f) {
    unsigned u = __float_as_uint(f);
    unsigned r = u + 0x7FFFu + ((u >> 16) & 1u);   // round-to-nearest-even
    return (unsigned short)(r >> 16);
}

// acc swizzle: feature f of node nd at acc[nd*64 + (f ^ ((nd&7)<<3))]
__device__ __forceinline__ int SW(int nd, int f) { return (nd << 6) + (f ^ ((nd & 7) << 3)); }

// ---------------- P1: per-(partition,bucket) histogram + x->bf16 + W2->bf16 ----------------
__global__ __launch_bounds__(256) void p1_count_cvt(const int* __restrict__ ei,
                                                    const float* __restrict__ x,
                                                    const float* __restrict__ Wl,
                                                    const float* __restrict__ Wr,
                                                    int* __restrict__ cnt_mat,
                                                    unsigned short* __restrict__ xh,
                                                    unsigned short* __restrict__ w2h)
{
    __shared__ int h[NBUCK];
    int t = threadIdx.x, blk = blockIdx.x;
    for (int i = t; i < NBUCK; i += 256) h[i] = 0;
    __syncthreads();
    int s = blk * EPP;
    int e_end = min(s + EPP, N_EDGES);
    for (int i = s + t; i < e_end; i += 256)
        atomicAdd(&h[ei[N_EDGES + i] / NPB], 1);
    // x -> bf16, grid-stride over 800000 float4 (~3 iters/thread)
    for (int gi = blk * 256 + t; gi < N_NODES * 16; gi += NPART * 256) {
        float4 v = ((const float4*)x)[gi];
        ushort4 o;
        o.x = f2bf(v.x); o.y = f2bf(v.y); o.z = f2bf(v.z); o.w = f2bf(v.w);
        ((ushort4*)xh)[gi] = o;
    }
    // W2h[o] = [Wr[o] | Wl[o]] bf16 (blocks 0..127, one out-row each)
    if (blk < 128 && t < 64) {
        w2h[blk * 128 + t]      = f2bf(Wr[blk * 64 + t]);
        w2h[blk * 128 + 64 + t] = f2bf(Wl[blk * 64 + t]);
    }
    __syncthreads();
    for (int b = t; b < NBUCK; b += 256) cnt_mat[b * NPART + blk] = h[b];
}

// ---------------- rowsum: tot[b] = sum of cnt_mat row b ----------------
__global__ __launch_bounds__(256) void rowsum(const int* __restrict__ cnt_mat,
                                              int* __restrict__ tot)
{
    __shared__ int ws[4];
    int t = threadIdx.x, b = blockIdx.x;
    int lane = t & 63, w = t >> 6;
    int4 v = ((const int4*)(cnt_mat + b * NPART))[t];   // 256 x int4 = 1024 ints
    int sv = v.x + v.y + v.z + v.w;
#pragma unroll
    for (int d = 32; d >= 1; d >>= 1) sv += __shfl_down(sv, d, 64);
    if (lane == 0) ws[w] = sv;
    __syncthreads();
    if (t == 0) tot[b] = ws[0] + ws[1] + ws[2] + ws[3];
}

// ---------------- rowscan2: cursors = bucket_start + exclusive scan of row ----------------
__global__ __launch_bounds__(256) void rowscan2(int* __restrict__ cnt_mat,
                                                const int* __restrict__ tot)
{
    __shared__ int bst_s;
    __shared__ int wtot[4];
    int t = threadIdx.x, b = blockIdx.x;
    int lane = t & 63, w = t >> 6;

    int4 mine = ((const int4*)(cnt_mat + b * NPART))[t];
    int s = mine.x + mine.y + mine.z + mine.w;
    int incl = s;
#pragma unroll
    for (int d = 1; d < 64; d <<= 1) {
        int u = __shfl_up(incl, d, 64);
        if (lane >= d) incl += u;
    }
    if (lane == 63) wtot[w] = incl;

    if (w == 0) {                       // redundant exclusive scan of 512 totals
        int carry = 0;
#pragma unroll
        for (int c = 0; c < 8; ++c) {
            int i = c * 64 + lane;
            int v = tot[i];
            int ic = v;
#pragma unroll
            for (int d = 1; d < 64; d <<= 1) {
                int u = __shfl_up(ic, d, 64);
                if (lane >= d) ic += u;
            }
            if (i == b) bst_s = carry + ic - v;
            carry += __shfl(ic, 63, 64);
        }
    }
    __syncthreads();
    int woff = 0;
    for (int j = 0; j < w; ++j) woff += wtot[j];
    int base = bst_s + woff + incl - s;
    int4 outv;
    outv.x = base;
    outv.y = base + mine.x;
    outv.z = base + mine.x + mine.y;
    outv.w = base + mine.x + mine.y + mine.z;
    ((int4*)(cnt_mat + b * NPART))[t] = outv;
}

// ---------------- place: 256 blocks, each covers 4 hist partitions ----------------
__global__ __launch_bounds__(256) void bucket_place(const int* __restrict__ ei,
                                                    const int* __restrict__ cnt_scan,
                                                    unsigned* __restrict__ ebuf)
{
    __shared__ int cur[NBUCK];
    int t = threadIdx.x, blk = blockIdx.x;
    for (int b = t; b < NBUCK; b += 256) cur[b] = cnt_scan[b * NPART + blk * 4];
    __syncthreads();
    int s = blk * 4 * EPP;
    int e_end = min(s + 4 * EPP, N_EDGES);
    for (int i = s + t; i < e_end; i += 256) {
        int src = ei[i], dst = ei[N_EDGES + i];
        int bkt = dst / NPB;
        int slot = atomicAdd(&cur[bkt], 1);
        ebuf[slot] = (unsigned)src | ((unsigned)(dst - bkt * NPB) << 16);
    }
}

// ---------------- fused gather (LDS int fixed-point, 16-deep MLP) + MFMA ----------------
__global__ __launch_bounds__(1024) void gather_mfma(const unsigned short* __restrict__ xh,
                                                    const int* __restrict__ cnt_scan,
                                                    const unsigned* __restrict__ ebuf,
                                                    const unsigned short* __restrict__ w2h,
                                                    const float* __restrict__ bl,
                                                    float* __restrict__ out)
{
    __shared__ int acc[NPB * 64];                 // 25.1 KB
    __shared__ unsigned short wlds[128 * WLDS];   // 34.8 KB -> ~60.4 KB total, 2 blocks/CU
    __shared__ int dcnt[128];
    __shared__ int range_s[2];
    int t = threadIdx.x, b = blockIdx.x;
    int lane = t & 63, w = t >> 6;                // 16 waves

#pragma unroll
    for (int c = 0; c < 2; ++c) {
        int idx = c * 1024 + t;
        int o = idx >> 4, kc = idx & 15;
        bf16x8 v = *(const bf16x8*)(w2h + o * 128 + kc * 8);
        *(bf16x8*)(&wlds[o * WLDS + kc * 8]) = v;
    }
    if (t == 0) {
        range_s[0] = cnt_scan[b * NPART];
        range_s[1] = (b < NBUCK - 1) ? cnt_scan[(b + 1) * NPART] : N_EDGES;
    }
    for (int i = t; i < NPB * 64; i += 1024) acc[i] = 0;
    if (t < 128) dcnt[t] = 0;
    __syncthreads();

    int bs = range_s[0], be = range_s[1];

    for (int e = bs + t; e < be; e += 1024)
        atomicAdd(&dcnt[(ebuf[e] >> 16) & 127], 1);

    // 16 outstanding 128B row loads per wave
    for (int e0 = bs + w * 64; e0 < be; e0 += 1024) {
        int m = be - e0; if (m > 64) m = 64;
        unsigned pv = (lane < m) ? ebuf[e0 + lane] : 0u;
        for (int k = 0; k < m; k += 16) {
            unsigned p[16]; int fx[16];
#pragma unroll
            for (int u = 0; u < 16; ++u) p[u] = __shfl(pv, k + u, 64);
#pragma unroll
            for (int u = 0; u < 16; ++u) {
                unsigned short hv = xh[(size_t)(p[u] & 0xFFFFu) * IN_DIM + lane];
                fx[u] = __float2int_rn(__uint_as_float((unsigned)hv << 16) * FIXSCALE);
            }
#pragma unroll
            for (int u = 0; u < 16; ++u)
                if (k + u < m)
                    atomicAdd(&acc[SW((p[u] >> 16) & 127, lane)], fx[u]);
        }
    }
    __syncthreads();

    // -------- MFMA: out = [x | mean] @ W2^T + b  (7 strips x 2 halves = 14 tasks) --------
    if (w < 14) {
        int strip = w >> 1, hf = w & 1;
        int row = lane & 15, q = lane >> 4;
        int in_node = strip * 16 + row;
        int in_c = (in_node < NPB) ? in_node : (NPB - 1);
        int gn = b * NPB + in_c;
        size_t nrow = (size_t)((gn < N_NODES) ? gn : (N_NODES - 1));

        bf16x8 a[4];
        a[0] = *(const bf16x8*)(xh + nrow * IN_DIM + q * 8);
        a[1] = *(const bf16x8*)(xh + nrow * IN_DIM + q * 8 + 32);

        int deg = dcnt[in_c];
        float sc = deg ? INVFIX / (float)deg : 0.0f;
        bf16x8 a2, a3;
#pragma unroll
        for (int j = 0; j < 8; ++j) {
            a2[j] = (short)f2bf((float)acc[SW(in_c, q * 8 + j)] * sc);
            a3[j] = (short)f2bf((float)acc[SW(in_c, 32 + q * 8 + j)] * sc);
        }
        a[2] = a2; a[3] = a3;

        f32x4 accf[4];
#pragma unroll
        for (int jj = 0; jj < 4; ++jj) accf[jj] = (f32x4){0.f, 0.f, 0.f, 0.f};

#pragma unroll
        for (int jj = 0; jj < 4; ++jj) {
            int ot = hf * 4 + jj;
            const unsigned short* wb = &wlds[(ot * 16 + row) * WLDS + q * 8];
#pragma unroll
            for (int s = 0; s < 4; ++s) {
                bf16x8 bfrag = *(const bf16x8*)(wb + s * 32);
                accf[jj] = __builtin_amdgcn_mfma_f32_16x16x32_bf16(a[s], bfrag, accf[jj], 0, 0, 0);
            }
        }

#pragma unroll
        for (int jj = 0; jj < 4; ++jj) {
            int ot = hf * 4 + jj;
            float bias = bl[ot * 16 + row];
#pragma unroll
            for (int r = 0; r < 4; ++r) {
                int loc = strip * 16 + q * 4 + r;
                int n = b * NPB + loc;
                if (loc < NPB && n < N_NODES)
                    out[(size_t)n * OUT_DIM + ot * 16 + row] = accf[jj][r] + bias;
            }
        }
    }
}

extern "C" void kernel_launch(void* const* d_in, const int* in_sizes, int n_in,
                              void* d_out, int out_size, void* d_ws, size_t ws_size,
                              hipStream_t stream) {
    const float* x  = (const float*)d_in[0];
    const int*   ei = (const int*)d_in[1];
    const float* Wl = (const float*)d_in[2];
    const float* bl = (const float*)d_in[3];
    const float* Wr = (const float*)d_in[4];
    float* out = (float*)d_out;

    // ws layout (~12 MB):
    int*            cnt_mat = (int*)d_ws;                               // 512*1024 ints
    int*            tot     = cnt_mat + NBUCK * NPART;                  // 512 ints
    unsigned*       ebuf    = (unsigned*)(tot + NBUCK);                 // 800000 uints
    unsigned short* xh      = (unsigned short*)(ebuf + N_EDGES);        // 3.2M bf16
    unsigned short* w2h     = xh + (size_t)N_NODES * IN_DIM;            // 16384 bf16

    p1_count_cvt<<<NPART, 256, 0, stream>>>(ei, x, Wl, Wr, cnt_mat, xh, w2h);
    rowsum<<<NBUCK, 256, 0, stream>>>(cnt_mat, tot);
    rowscan2<<<NBUCK, 256, 0, stream>>>(cnt_mat, tot);
    bucket_place<<<NPLACE, 256, 0, stream>>>(ei, cnt_mat, ebuf);
    gather_mfma<<<NBUCK, 1024, 0, stream>>>(xh, cnt_mat, ebuf, w2h, bl, out);
}

// Round 18
// 67.747 us; speedup vs baseline: 1.3914x; 1.0152x over previous
//
#include <hip/hip_runtime.h>

#define N_NODES 50000
#define IN_DIM 64
#define OUT_DIM 128
#define N_EDGES 800000

#define NPART 1024                  // histogram partitions
#define EPP 782                     // ceil(N_EDGES / NPART)
#define NPLACE 256                  // place blocks (4 hist partitions each)
#define NBUCK 512                   // buckets: exactly 2 blocks/CU on 256 CUs
#define NPB 98                      // nodes per bucket (512*98 = 50176 >= 50000)
#define WLDS 136                    // padded bf16 row stride: bank step 4 -> 2-way (free)
#define QSCALE 256.0f               // int16 fixed-point scale (|x|<6 -> |q|<1536)
#define INVQ (1.0f / 256.0f)

typedef __attribute__((ext_vector_type(8))) short bf16x8;
typedef __attribute__((ext_vector_type(4))) float f32x4;

__device__ __forceinline__ unsigned short f2bf(float f) {
    unsigned u = __float_as_uint(f);
    unsigned r = u + 0x7FFFu + ((u >> 16) & 1u);   // round-to-nearest-even
    return (unsigned short)(r >> 16);
}

// acc swizzle: feature f of node nd at acc[nd*64 + (f ^ ((nd&7)<<3))]
__device__ __forceinline__ int SW(int nd, int f) { return (nd << 6) + (f ^ ((nd & 7) << 3)); }

// ---------------- P1: histogram + x->bf16 + x->int16-fixed + W2->bf16 ----------------
__global__ __launch_bounds__(256) void p1_count_cvt(const int* __restrict__ ei,
                                                    const float* __restrict__ x,
                                                    const float* __restrict__ Wl,
                                                    const float* __restrict__ Wr,
                                                    int* __restrict__ cnt_mat,
                                                    unsigned short* __restrict__ xh,
                                                    short* __restrict__ xq,
                                                    unsigned short* __restrict__ w2h)
{
    __shared__ int h[NBUCK];
    int t = threadIdx.x, blk = blockIdx.x;
    for (int i = t; i < NBUCK; i += 256) h[i] = 0;
    __syncthreads();
    int s = blk * EPP;
    int e_end = min(s + EPP, N_EDGES);
    for (int i = s + t; i < e_end; i += 256)
        atomicAdd(&h[ei[N_EDGES + i] / NPB], 1);
    // x -> bf16 + int16 fixed, grid-stride over 800000 float4
    for (int gi = blk * 256 + t; gi < N_NODES * 16; gi += NPART * 256) {
        float4 v = ((const float4*)x)[gi];
        ushort4 o;
        o.x = f2bf(v.x); o.y = f2bf(v.y); o.z = f2bf(v.z); o.w = f2bf(v.w);
        ((ushort4*)xh)[gi] = o;
        short4 q;
        q.x = (short)__float2int_rn(v.x * QSCALE);
        q.y = (short)__float2int_rn(v.y * QSCALE);
        q.z = (short)__float2int_rn(v.z * QSCALE);
        q.w = (short)__float2int_rn(v.w * QSCALE);
        ((short4*)xq)[gi] = q;
    }
    // W2h[o] = [Wr[o] | Wl[o]] bf16 (blocks 0..127, one out-row each)
    if (blk < 128 && t < 64) {
        w2h[blk * 128 + t]      = f2bf(Wr[blk * 64 + t]);
        w2h[blk * 128 + 64 + t] = f2bf(Wl[blk * 64 + t]);
    }
    __syncthreads();
    for (int b = t; b < NBUCK; b += 256) cnt_mat[b * NPART + blk] = h[b];
}

// ---------------- rowsum: tot[b] = sum of cnt_mat row b ----------------
__global__ __launch_bounds__(256) void rowsum(const int* __restrict__ cnt_mat,
                                              int* __restrict__ tot)
{
    __shared__ int ws[4];
    int t = threadIdx.x, b = blockIdx.x;
    int lane = t & 63, w = t >> 6;
    int4 v = ((const int4*)(cnt_mat + b * NPART))[t];
    int sv = v.x + v.y + v.z + v.w;
#pragma unroll
    for (int d = 32; d >= 1; d >>= 1) sv += __shfl_down(sv, d, 64);
    if (lane == 0) ws[w] = sv;
    __syncthreads();
    if (t == 0) tot[b] = ws[0] + ws[1] + ws[2] + ws[3];
}

// ---------------- rowscan2: cursors = bucket_start + exclusive scan of row ----------------
__global__ __launch_bounds__(256) void rowscan2(int* __restrict__ cnt_mat,
                                                const int* __restrict__ tot)
{
    __shared__ int bst_s;
    __shared__ int wtot[4];
    int t = threadIdx.x, b = blockIdx.x;
    int lane = t & 63, w = t >> 6;

    int4 mine = ((const int4*)(cnt_mat + b * NPART))[t];
    int s = mine.x + mine.y + mine.z + mine.w;
    int incl = s;
#pragma unroll
    for (int d = 1; d < 64; d <<= 1) {
        int u = __shfl_up(incl, d, 64);
        if (lane >= d) incl += u;
    }
    if (lane == 63) wtot[w] = incl;

    if (w == 0) {                       // redundant exclusive scan of 512 totals
        int carry = 0;
#pragma unroll
        for (int c = 0; c < 8; ++c) {
            int i = c * 64 + lane;
            int v = tot[i];
            int ic = v;
#pragma unroll
            for (int d = 1; d < 64; d <<= 1) {
                int u = __shfl_up(ic, d, 64);
                if (lane >= d) ic += u;
            }
            if (i == b) bst_s = carry + ic - v;
            carry += __shfl(ic, 63, 64);
        }
    }
    __syncthreads();
    int woff = 0;
    for (int j = 0; j < w; ++j) woff += wtot[j];
    int base = bst_s + woff + incl - s;
    int4 outv;
    outv.x = base;
    outv.y = base + mine.x;
    outv.z = base + mine.x + mine.y;
    outv.w = base + mine.x + mine.y + mine.z;
    ((int4*)(cnt_mat + b * NPART))[t] = outv;
}

// ---------------- place: 256 blocks, each covers 4 hist partitions ----------------
__global__ __launch_bounds__(256) void bucket_place(const int* __restrict__ ei,
                                                    const int* __restrict__ cnt_scan,
                                                    unsigned* __restrict__ ebuf)
{
    __shared__ int cur[NBUCK];
    int t = threadIdx.x, blk = blockIdx.x;
    for (int b = t; b < NBUCK; b += 256) cur[b] = cnt_scan[b * NPART + blk * 4];
    __syncthreads();
    int s = blk * 4 * EPP;
    int e_end = min(s + 4 * EPP, N_EDGES);
    for (int i = s + t; i < e_end; i += 256) {
        int src = ei[i], dst = ei[N_EDGES + i];
        int bkt = dst / NPB;
        int slot = atomicAdd(&cur[bkt], 1);
        ebuf[slot] = (unsigned)src | ((unsigned)(dst - bkt * NPB) << 16);
    }
}

// ---------------- fused gather (scalar edge walk, int16 accumulate) + MFMA ----------------
__global__ __launch_bounds__(1024) void gather_mfma(const unsigned short* __restrict__ xh,
                                                    const short* __restrict__ xq,
                                                    const int* __restrict__ cnt_scan,
                                                    const unsigned* __restrict__ ebuf,
                                                    const unsigned short* __restrict__ w2h,
                                                    const float* __restrict__ bl,
                                                    float* __restrict__ out)
{
    __shared__ int acc[NPB * 64];                 // 25.1 KB
    __shared__ unsigned short wlds[128 * WLDS];   // 34.8 KB -> ~60.4 KB, 2 blocks/CU
    __shared__ int dcnt[128];
    __shared__ int range_s[2];
    int t = threadIdx.x, b = blockIdx.x;
    int lane = t & 63, w = t >> 6;                // 16 waves

#pragma unroll
    for (int c = 0; c < 2; ++c) {
        int idx = c * 1024 + t;
        int o = idx >> 4, kc = idx & 15;
        bf16x8 v = *(const bf16x8*)(w2h + o * 128 + kc * 8);
        *(bf16x8*)(&wlds[o * WLDS + kc * 8]) = v;
    }
    if (t == 0) {
        range_s[0] = cnt_scan[b * NPART];
        range_s[1] = (b < NBUCK - 1) ? cnt_scan[(b + 1) * NPART] : N_EDGES;
    }
    for (int i = t; i < NPB * 64; i += 1024) acc[i] = 0;
    if (t < 128) dcnt[t] = 0;
    __syncthreads();

    int bs = __builtin_amdgcn_readfirstlane(range_s[0]);
    int be = __builtin_amdgcn_readfirstlane(range_s[1]);

    for (int e = bs + t; e < be; e += 1024)
        atomicAdd(&dcnt[(ebuf[e] >> 16) & 127], 1);

    // scalar-uniform edge walk: wave wu owns 64-edge chunks strided by 16 waves.
    // Edge words come in via s_load (uniform addr); src/nd math on SALU;
    // per edge: 1 global_load_sshort (saddr+lane form) + 1 ds_add. No cvt, no shfl.
    int wu = __builtin_amdgcn_readfirstlane(w);
    for (int e0 = bs + wu * 64; e0 < be; e0 += 1024) {
        int m = be - e0; if (m > 64) m = 64;
        if (m == 64) {
#pragma unroll
            for (int k = 0; k < 64; k += 16) {
                unsigned p[16];
#pragma unroll
                for (int u = 0; u < 16; ++u) p[u] = ebuf[e0 + k + u];   // uniform -> s_load
                int hv[16];
#pragma unroll
                for (int u = 0; u < 16; ++u) {
                    int src = (int)(p[u] & 0xFFFFu);
                    hv[u] = (int)xq[src * IN_DIM + lane];               // sext s16 load
                }
                int sa[16];
#pragma unroll
                for (int u = 0; u < 16; ++u)
                    sa[u] = SW((int)((p[u] >> 16) & 127u), lane);
#pragma unroll
                for (int u = 0; u < 16; ++u) atomicAdd(&acc[sa[u]], hv[u]);
            }
        } else {
            for (int k = 0; k < m; ++k) {
                unsigned p = ebuf[e0 + k];
                int src = (int)(p & 0xFFFFu);
                int hv = (int)xq[src * IN_DIM + lane];
                atomicAdd(&acc[SW((int)((p >> 16) & 127u), lane)], hv);
            }
        }
    }
    __syncthreads();

    // -------- MFMA: out = [x | mean] @ W2^T + b  (7 strips x 2 halves = 14 tasks) --------
    if (w < 14) {
        int strip = w >> 1, hf = w & 1;
        int row = lane & 15, q = lane >> 4;
        int in_node = strip * 16 + row;
        int in_c = (in_node < NPB) ? in_node : (NPB - 1);
        int gn = b * NPB + in_c;
        size_t nrow = (size_t)((gn < N_NODES) ? gn : (N_NODES - 1));

        bf16x8 a[4];
        a[0] = *(const bf16x8*)(xh + nrow * IN_DIM + q * 8);
        a[1] = *(const bf16x8*)(xh + nrow * IN_DIM + q * 8 + 32);

        int deg = dcnt[in_c];
        float sc = deg ? INVQ / (float)deg : 0.0f;
        bf16x8 a2, a3;
#pragma unroll
        for (int j = 0; j < 8; ++j) {
            a2[j] = (short)f2bf((float)acc[SW(in_c, q * 8 + j)] * sc);
            a3[j] = (short)f2bf((float)acc[SW(in_c, 32 + q * 8 + j)] * sc);
        }
        a[2] = a2; a[3] = a3;

        f32x4 accf[4];
#pragma unroll
        for (int jj = 0; jj < 4; ++jj) accf[jj] = (f32x4){0.f, 0.f, 0.f, 0.f};

#pragma unroll
        for (int jj = 0; jj < 4; ++jj) {
            int ot = hf * 4 + jj;
            const unsigned short* wb = &wlds[(ot * 16 + row) * WLDS + q * 8];
#pragma unroll
            for (int s = 0; s < 4; ++s) {
                bf16x8 bfrag = *(const bf16x8*)(wb + s * 32);
                accf[jj] = __builtin_amdgcn_mfma_f32_16x16x32_bf16(a[s], bfrag, accf[jj], 0, 0, 0);
            }
        }

#pragma unroll
        for (int jj = 0; jj < 4; ++jj) {
            int ot = hf * 4 + jj;
            float bias = bl[ot * 16 + row];
#pragma unroll
            for (int r = 0; r < 4; ++r) {
                int loc = strip * 16 + q * 4 + r;
                int n = b * NPB + loc;
                if (loc < NPB && n < N_NODES)
                    out[(size_t)n * OUT_DIM + ot * 16 + row] = accf[jj][r] + bias;
            }
        }
    }
}

extern "C" void kernel_launch(void* const* d_in, const int* in_sizes, int n_in,
                              void* d_out, int out_size, void* d_ws, size_t ws_size,
                              hipStream_t stream) {
    const float* x  = (const float*)d_in[0];
    const int*   ei = (const int*)d_in[1];
    const float* Wl = (const float*)d_in[2];
    const float* bl = (const float*)d_in[3];
    const float* Wr = (const float*)d_in[4];
    float* out = (float*)d_out;

    // ws layout (~18.4 MB):
    int*            cnt_mat = (int*)d_ws;                               // 512*1024 ints
    int*            tot     = cnt_mat + NBUCK * NPART;                  // 512 ints
    unsigned*       ebuf    = (unsigned*)(tot + NBUCK);                 // 800000 uints
    unsigned short* xh      = (unsigned short*)(ebuf + N_EDGES);        // 3.2M bf16
    short*          xq      = (short*)(xh + (size_t)N_NODES * IN_DIM);  // 3.2M int16
    unsigned short* w2h     = (unsigned short*)(xq + (size_t)N_NODES * IN_DIM); // 16384 bf16

    p1_count_cvt<<<NPART, 256, 0, stream>>>(ei, x, Wl, Wr, cnt_mat, xh, xq, w2h);
    rowsum<<<NBUCK, 256, 0, stream>>>(cnt_mat, tot);
    rowscan2<<<NBUCK, 256, 0, stream>>>(cnt_mat, tot);
    bucket_place<<<NPLACE, 256, 0, stream>>>(ei, cnt_mat, ebuf);
    gather_mfma<<<NBUCK, 1024, 0, stream>>>(xh, xq, cnt_mat, ebuf, w2h, bl, out);
}

// Round 19
// 64.274 us; speedup vs baseline: 1.4665x; 1.0540x over previous
//
#include <hip/hip_runtime.h>

#define N_NODES 50000
#define IN_DIM 64
#define OUT_DIM 128
#define N_EDGES 800000

#define NPART 512                   // histogram partitions
#define EPP 1563                    // ceil(N_EDGES / NPART)
#define NPLACE 256                  // place blocks (2 hist partitions each)
#define NBUCK 512                   // buckets: exactly 2 blocks/CU on 256 CUs
#define NPB 98                      // nodes per bucket (512*98 = 50176 >= 50000)
#define WLDS 136                    // padded bf16 row stride: bank step 4 -> 2-way (free)
#define QSCALE 256.0f               // int16 fixed-point scale (|x|<6 -> |q|<1536)
#define INVQ (1.0f / 256.0f)

typedef __attribute__((ext_vector_type(8))) short bf16x8;
typedef __attribute__((ext_vector_type(8))) short s16x8;
typedef __attribute__((ext_vector_type(4))) float f32x4;

__device__ __forceinline__ unsigned short f2bf(float f) {
    unsigned u = __float_as_uint(f);
    unsigned r = u + 0x7FFFu + ((u >> 16) & 1u);   // round-to-nearest-even
    return (unsigned short)(r >> 16);
}

// acc swizzle: feature f of node nd at acc[nd*64 + (f ^ ((nd&7)<<3))]
__device__ __forceinline__ int SW(int nd, int f) { return (nd << 6) + (f ^ ((nd & 7) << 3)); }

// ---------------- P1: histogram + x->int16-fixed + W2->bf16 ----------------
__global__ __launch_bounds__(256) void p1_count_cvt(const int* __restrict__ ei,
                                                    const float* __restrict__ x,
                                                    const float* __restrict__ Wl,
                                                    const float* __restrict__ Wr,
                                                    int* __restrict__ cnt_mat,
                                                    short* __restrict__ xq,
                                                    unsigned short* __restrict__ w2h)
{
    __shared__ int h[NBUCK];
    int t = threadIdx.x, blk = blockIdx.x;
    for (int i = t; i < NBUCK; i += 256) h[i] = 0;
    __syncthreads();
    int s = blk * EPP;
    int e_end = min(s + EPP, N_EDGES);
    for (int i = s + t; i < e_end; i += 256)
        atomicAdd(&h[ei[N_EDGES + i] / NPB], 1);
    // x -> int16 fixed, grid-stride over 800000 float4 (~6 iters/thread)
    for (int gi = blk * 256 + t; gi < N_NODES * 16; gi += NPART * 256) {
        float4 v = ((const float4*)x)[gi];
        short4 q;
        q.x = (short)__float2int_rn(v.x * QSCALE);
        q.y = (short)__float2int_rn(v.y * QSCALE);
        q.z = (short)__float2int_rn(v.z * QSCALE);
        q.w = (short)__float2int_rn(v.w * QSCALE);
        ((short4*)xq)[gi] = q;
    }
    // W2h[o] = [Wr[o] | Wl[o]] bf16 (blocks 0..127, one out-row each)
    if (blk < 128 && t < 64) {
        w2h[blk * 128 + t]      = f2bf(Wr[blk * 64 + t]);
        w2h[blk * 128 + 64 + t] = f2bf(Wl[blk * 64 + t]);
    }
    __syncthreads();
    for (int b = t; b < NBUCK; b += 256) cnt_mat[b * NPART + blk] = h[b];
}

// ---------------- rowsum: tot[b] = sum of cnt_mat row b (512 ints = 256 x int2) ----------------
__global__ __launch_bounds__(256) void rowsum(const int* __restrict__ cnt_mat,
                                              int* __restrict__ tot)
{
    __shared__ int ws[4];
    int t = threadIdx.x, b = blockIdx.x;
    int lane = t & 63, w = t >> 6;
    int2 v = ((const int2*)(cnt_mat + b * NPART))[t];
    int sv = v.x + v.y;
#pragma unroll
    for (int d = 32; d >= 1; d >>= 1) sv += __shfl_down(sv, d, 64);
    if (lane == 0) ws[w] = sv;
    __syncthreads();
    if (t == 0) tot[b] = ws[0] + ws[1] + ws[2] + ws[3];
}

// ---------------- rowscan2: cursors = bucket_start + exclusive scan of row ----------------
__global__ __launch_bounds__(256) void rowscan2(int* __restrict__ cnt_mat,
                                                const int* __restrict__ tot)
{
    __shared__ int bst_s;
    __shared__ int wtot[4];
    int t = threadIdx.x, b = blockIdx.x;
    int lane = t & 63, w = t >> 6;

    int2 mine = ((const int2*)(cnt_mat + b * NPART))[t];
    int s = mine.x + mine.y;
    int incl = s;
#pragma unroll
    for (int d = 1; d < 64; d <<= 1) {
        int u = __shfl_up(incl, d, 64);
        if (lane >= d) incl += u;
    }
    if (lane == 63) wtot[w] = incl;

    if (w == 0) {                       // redundant exclusive scan of 512 totals
        int carry = 0;
#pragma unroll
        for (int c = 0; c < 8; ++c) {
            int i = c * 64 + lane;
            int v = tot[i];
            int ic = v;
#pragma unroll
            for (int d = 1; d < 64; d <<= 1) {
                int u = __shfl_up(ic, d, 64);
                if (lane >= d) ic += u;
            }
            if (i == b) bst_s = carry + ic - v;
            carry += __shfl(ic, 63, 64);
        }
    }
    __syncthreads();
    int woff = 0;
    for (int j = 0; j < w; ++j) woff += wtot[j];
    int base = bst_s + woff + incl - s;
    int2 outv;
    outv.x = base;
    outv.y = base + mine.x;
    ((int2*)(cnt_mat + b * NPART))[t] = outv;
}

// ---------------- place: 256 blocks, each covers 2 hist partitions ----------------
__global__ __launch_bounds__(256) void bucket_place(const int* __restrict__ ei,
                                                    const int* __restrict__ cnt_scan,
                                                    unsigned* __restrict__ ebuf)
{
    __shared__ int cur[NBUCK];
    int t = threadIdx.x, blk = blockIdx.x;
    for (int b = t; b < NBUCK; b += 256) cur[b] = cnt_scan[b * NPART + blk * 2];
    __syncthreads();
    int s = blk * 2 * EPP;
    int e_end = min(s + 2 * EPP, N_EDGES);
    for (int i = s + t; i < e_end; i += 256) {
        int src = ei[i], dst = ei[N_EDGES + i];
        int bkt = dst / NPB;
        int slot = atomicAdd(&cur[bkt], 1);
        ebuf[slot] = (unsigned)src | ((unsigned)(dst - bkt * NPB) << 16);
    }
}

// ---------------- fused gather (scalar edge walk, int16 accumulate) + MFMA ----------------
__global__ __launch_bounds__(1024) void gather_mfma(const short* __restrict__ xq,
                                                    const int* __restrict__ cnt_scan,
                                                    const unsigned* __restrict__ ebuf,
                                                    const unsigned short* __restrict__ w2h,
                                                    const float* __restrict__ bl,
                                                    float* __restrict__ out)
{
    __shared__ int acc[NPB * 64];                 // 25.1 KB
    __shared__ unsigned short wlds[128 * WLDS];   // 34.8 KB -> ~60.4 KB, 2 blocks/CU
    __shared__ int dcnt[128];
    __shared__ int range_s[2];
    int t = threadIdx.x, b = blockIdx.x;
    int lane = t & 63, w = t >> 6;                // 16 waves

#pragma unroll
    for (int c = 0; c < 2; ++c) {
        int idx = c * 1024 + t;
        int o = idx >> 4, kc = idx & 15;
        bf16x8 v = *(const bf16x8*)(w2h + o * 128 + kc * 8);
        *(bf16x8*)(&wlds[o * WLDS + kc * 8]) = v;
    }
    if (t == 0) {
        range_s[0] = cnt_scan[b * NPART];
        range_s[1] = (b < NBUCK - 1) ? cnt_scan[(b + 1) * NPART] : N_EDGES;
    }
    for (int i = t; i < NPB * 64; i += 1024) acc[i] = 0;
    if (t < 128) dcnt[t] = 0;
    __syncthreads();

    int bs = __builtin_amdgcn_readfirstlane(range_s[0]);
    int be = __builtin_amdgcn_readfirstlane(range_s[1]);

    for (int e = bs + t; e < be; e += 1024)
        atomicAdd(&dcnt[(ebuf[e] >> 16) & 127], 1);

    // scalar-uniform edge walk: wave wu owns 64-edge chunks strided by 16 waves.
    int wu = __builtin_amdgcn_readfirstlane(w);
    for (int e0 = bs + wu * 64; e0 < be; e0 += 1024) {
        int m = be - e0; if (m > 64) m = 64;
        if (m == 64) {
#pragma unroll
            for (int k = 0; k < 64; k += 16) {
                unsigned p[16];
#pragma unroll
                for (int u = 0; u < 16; ++u) p[u] = ebuf[e0 + k + u];   // uniform -> s_load
                int hv[16];
#pragma unroll
                for (int u = 0; u < 16; ++u) {
                    int src = (int)(p[u] & 0xFFFFu);
                    hv[u] = (int)xq[src * IN_DIM + lane];               // sext s16 load
                }
                int sa[16];
#pragma unroll
                for (int u = 0; u < 16; ++u)
                    sa[u] = SW((int)((p[u] >> 16) & 127u), lane);
#pragma unroll
                for (int u = 0; u < 16; ++u) atomicAdd(&acc[sa[u]], hv[u]);
            }
        } else {
            for (int k = 0; k < m; ++k) {
                unsigned p = ebuf[e0 + k];
                int src = (int)(p & 0xFFFFu);
                int hv = (int)xq[src * IN_DIM + lane];
                atomicAdd(&acc[SW((int)((p >> 16) & 127u), lane)], hv);
            }
        }
    }
    __syncthreads();

    // -------- MFMA: out = [x | mean] @ W2^T + b  (7 strips x 2 halves = 14 tasks) --------
    if (w < 14) {
        int strip = w >> 1, hf = w & 1;
        int row = lane & 15, q = lane >> 4;
        int in_node = strip * 16 + row;
        int in_c = (in_node < NPB) ? in_node : (NPB - 1);
        int gn = b * NPB + in_c;
        size_t nrow = (size_t)((gn < N_NODES) ? gn : (N_NODES - 1));

        // A-operand rows 0..1: x from xq (dequant int16 -> bf16)
        s16x8 q0 = *(const s16x8*)(xq + nrow * IN_DIM + q * 8);
        s16x8 q1 = *(const s16x8*)(xq + nrow * IN_DIM + q * 8 + 32);
        bf16x8 a[4];
        bf16x8 a0, a1;
#pragma unroll
        for (int j = 0; j < 8; ++j) {
            a0[j] = (short)f2bf((float)q0[j] * INVQ);
            a1[j] = (short)f2bf((float)q1[j] * INVQ);
        }
        a[0] = a0; a[1] = a1;

        int deg = dcnt[in_c];
        float sc = deg ? INVQ / (float)deg : 0.0f;
        bf16x8 a2, a3;
#pragma unroll
        for (int j = 0; j < 8; ++j) {
            a2[j] = (short)f2bf((float)acc[SW(in_c, q * 8 + j)] * sc);
            a3[j] = (short)f2bf((float)acc[SW(in_c, 32 + q * 8 + j)] * sc);
        }
        a[2] = a2; a[3] = a3;

        f32x4 accf[4];
#pragma unroll
        for (int jj = 0; jj < 4; ++jj) accf[jj] = (f32x4){0.f, 0.f, 0.f, 0.f};

#pragma unroll
        for (int jj = 0; jj < 4; ++jj) {
            int ot = hf * 4 + jj;
            const unsigned short* wb = &wlds[(ot * 16 + row) * WLDS + q * 8];
#pragma unroll
            for (int s = 0; s < 4; ++s) {
                bf16x8 bfrag = *(const bf16x8*)(wb + s * 32);
                accf[jj] = __builtin_amdgcn_mfma_f32_16x16x32_bf16(a[s], bfrag, accf[jj], 0, 0, 0);
            }
        }

#pragma unroll
        for (int jj = 0; jj < 4; ++jj) {
            int ot = hf * 4 + jj;
            float bias = bl[ot * 16 + row];
#pragma unroll
            for (int r = 0; r < 4; ++r) {
                int loc = strip * 16 + q * 4 + r;
                int n = b * NPB + loc;
                if (loc < NPB && n < N_NODES)
                    out[(size_t)n * OUT_DIM + ot * 16 + row] = accf[jj][r] + bias;
            }
        }
    }
}

extern "C" void kernel_launch(void* const* d_in, const int* in_sizes, int n_in,
                              void* d_out, int out_size, void* d_ws, size_t ws_size,
                              hipStream_t stream) {
    const float* x  = (const float*)d_in[0];
    const int*   ei = (const int*)d_in[1];
    const float* Wl = (const float*)d_in[2];
    const float* bl = (const float*)d_in[3];
    const float* Wr = (const float*)d_in[4];
    float* out = (float*)d_out;

    // ws layout (~10.7 MB):
    int*            cnt_mat = (int*)d_ws;                               // 512*512 ints
    int*            tot     = cnt_mat + NBUCK * NPART;                  // 512 ints
    unsigned*       ebuf    = (unsigned*)(tot + NBUCK);                 // 800000 uints
    short*          xq      = (short*)(ebuf + N_EDGES);                 // 3.2M int16
    unsigned short* w2h     = (unsigned short*)(xq + (size_t)N_NODES * IN_DIM); // 16384 bf16

    p1_count_cvt<<<NPART, 256, 0, stream>>>(ei, x, Wl, Wr, cnt_mat, xq, w2h);
    rowsum<<<NBUCK, 256, 0, stream>>>(cnt_mat, tot);
    rowscan2<<<NBUCK, 256, 0, stream>>>(cnt_mat, tot);
    bucket_place<<<NPLACE, 256, 0, stream>>>(ei, cnt_mat, ebuf);
    gather_mfma<<<NBUCK, 1024, 0, stream>>>(xq, cnt_mat, ebuf, w2h, bl, out);
}